// Round 1
// baseline (2749.954 us; speedup 1.0000x reference)
//
#include <hip/hip_runtime.h>

#define HIDDEN 256
#define BM 128
#define BN 128
#define BK 16
#define LDP 132  // padded LDS row stride (floats): 16B-aligned, breaks bank patterns

// ---------------------------------------------------------------------------
// CSR build: histogram over dst, exclusive scan, fill
// ---------------------------------------------------------------------------
__global__ __launch_bounds__(256) void k_hist(const int* __restrict__ dst,
                                              int* __restrict__ deg, int E) {
  for (int e = blockIdx.x * blockDim.x + threadIdx.x; e < E;
       e += gridDim.x * blockDim.x)
    atomicAdd(&deg[dst[e]], 1);
}

__global__ __launch_bounds__(1024) void k_scan(const int* __restrict__ deg,
                                               int* __restrict__ row_ptr, int N) {
  __shared__ int s[1024];
  const int t = threadIdx.x;
  int run = 0;
  if (t == 0) row_ptr[0] = 0;
  for (int base = 0; base < N; base += 1024) {
    int idx = base + t;
    s[t] = (idx < N) ? deg[idx] : 0;
    __syncthreads();
    for (int off = 1; off < 1024; off <<= 1) {
      int add = (t >= off) ? s[t - off] : 0;
      __syncthreads();
      s[t] += add;
      __syncthreads();
    }
    if (idx < N) row_ptr[idx + 1] = run + s[t];
    run += s[1023];
    __syncthreads();
  }
}

__global__ __launch_bounds__(256) void k_dinv(const int* __restrict__ deg,
                                              float* __restrict__ dinv, int N) {
  int v = blockIdx.x * blockDim.x + threadIdx.x;
  if (v < N) dinv[v] = 1.0f / sqrtf((float)deg[v] + 1.0f);  // +1 self loop
}

__global__ __launch_bounds__(256) void k_fill(const int* __restrict__ src,
                                              const int* __restrict__ dst,
                                              const int* __restrict__ row_ptr,
                                              int* __restrict__ fill,
                                              int* __restrict__ csr, int E) {
  for (int e = blockIdx.x * blockDim.x + threadIdx.x; e < E;
       e += gridDim.x * blockDim.x) {
    int d = dst[e];
    int pos = atomicAdd(&fill[d], 1);
    csr[row_ptr[d] + pos] = src[e];
  }
}

// ---------------------------------------------------------------------------
// fp32 GEMM, C[M,256] = A[M,K] @ B[K,256], fused epilogue.
// EPI==0: C = relu(A@B + bias)      (aux = bias[256])
// EPI==1: C = rowscale[r] * (A@B)   (aux = rowscale[M])
// 256 threads = 4 waves; each wave owns a 64x64 quadrant, lane grid 8x8,
// 8x8 micro-tile per thread.
// ---------------------------------------------------------------------------
template <int EPI>
__global__ __launch_bounds__(256) void gemm256(const float* __restrict__ A,
                                               const float* __restrict__ B,
                                               const float* __restrict__ aux,
                                               float* __restrict__ C, int M,
                                               int K) {
  __shared__ float as[BK][LDP];
  __shared__ float bs[BK][LDP];
  const int t = threadIdx.x;
  const int row0 = blockIdx.x * BM;
  const int col0 = blockIdx.y * BN;

  const int w = t >> 6, l = t & 63;
  const int tr = ((w >> 1) << 6) + ((l >> 3) << 3);  // thread row offset
  const int tc = ((w & 1) << 6) + ((l & 7) << 3);    // thread col offset

  const int ar = t >> 2;        // A-tile row (first half)
  const int ak = (t & 3) << 2;  // A-tile k0
  const int br = t >> 5;        // B-tile row (first half)
  const int bc = (t & 31) << 2; // B-tile col

  float acc[8][8];
#pragma unroll
  for (int i = 0; i < 8; ++i)
#pragma unroll
    for (int j = 0; j < 8; ++j) acc[i][j] = 0.f;

  for (int k0 = 0; k0 < K; k0 += BK) {
    const int ra0 = row0 + ar, ra1 = row0 + ar + 64;
    float4 a0 = make_float4(0.f, 0.f, 0.f, 0.f), a1 = a0;
    if (ra0 < M) a0 = *(const float4*)&A[(size_t)ra0 * K + k0 + ak];
    if (ra1 < M) a1 = *(const float4*)&A[(size_t)ra1 * K + k0 + ak];
    float4 b0 = *(const float4*)&B[(size_t)(k0 + br) * HIDDEN + col0 + bc];
    float4 b1 = *(const float4*)&B[(size_t)(k0 + br + 8) * HIDDEN + col0 + bc];
    __syncthreads();
    as[ak + 0][ar] = a0.x;
    as[ak + 1][ar] = a0.y;
    as[ak + 2][ar] = a0.z;
    as[ak + 3][ar] = a0.w;
    as[ak + 0][ar + 64] = a1.x;
    as[ak + 1][ar + 64] = a1.y;
    as[ak + 2][ar + 64] = a1.z;
    as[ak + 3][ar + 64] = a1.w;
    *(float4*)&bs[br][bc] = b0;
    *(float4*)&bs[br + 8][bc] = b1;
    __syncthreads();
#pragma unroll
    for (int k = 0; k < BK; ++k) {
      float4 aa0 = *(const float4*)&as[k][tr];
      float4 aa1 = *(const float4*)&as[k][tr + 4];
      float4 bb0 = *(const float4*)&bs[k][tc];
      float4 bb1 = *(const float4*)&bs[k][tc + 4];
      float av[8] = {aa0.x, aa0.y, aa0.z, aa0.w, aa1.x, aa1.y, aa1.z, aa1.w};
      float bv[8] = {bb0.x, bb0.y, bb0.z, bb0.w, bb1.x, bb1.y, bb1.z, bb1.w};
#pragma unroll
      for (int i = 0; i < 8; ++i)
#pragma unroll
        for (int j = 0; j < 8; ++j) acc[i][j] += av[i] * bv[j];
    }
  }

  if (EPI == 0) {
    float bias[8];
#pragma unroll
    for (int j = 0; j < 8; ++j) bias[j] = aux[col0 + tc + j];
#pragma unroll
    for (int i = 0; i < 8; ++i) {
      int r = row0 + tr + i;
      if (r >= M) continue;
      float4 o0, o1;
      o0.x = fmaxf(acc[i][0] + bias[0], 0.f);
      o0.y = fmaxf(acc[i][1] + bias[1], 0.f);
      o0.z = fmaxf(acc[i][2] + bias[2], 0.f);
      o0.w = fmaxf(acc[i][3] + bias[3], 0.f);
      o1.x = fmaxf(acc[i][4] + bias[4], 0.f);
      o1.y = fmaxf(acc[i][5] + bias[5], 0.f);
      o1.z = fmaxf(acc[i][6] + bias[6], 0.f);
      o1.w = fmaxf(acc[i][7] + bias[7], 0.f);
      *(float4*)&C[(size_t)r * HIDDEN + col0 + tc] = o0;
      *(float4*)&C[(size_t)r * HIDDEN + col0 + tc + 4] = o1;
    }
  } else {
#pragma unroll
    for (int i = 0; i < 8; ++i) {
      int r = row0 + tr + i;
      if (r >= M) continue;
      float sc = aux[r];
      float4 o0, o1;
      o0.x = acc[i][0] * sc;
      o0.y = acc[i][1] * sc;
      o0.z = acc[i][2] * sc;
      o0.w = acc[i][3] * sc;
      o1.x = acc[i][4] * sc;
      o1.y = acc[i][5] * sc;
      o1.z = acc[i][6] * sc;
      o1.w = acc[i][7] * sc;
      *(float4*)&C[(size_t)r * HIDDEN + col0 + tc] = o0;
      *(float4*)&C[(size_t)r * HIDDEN + col0 + tc + 4] = o1;
    }
  }
}

// ---------------------------------------------------------------------------
// Gather aggregation + bias + BN + ReLU.
// One wave per node; lane l owns channels 4l..4l+3 (one float4 of the row).
// agg[v] = dinv[v]*(sum_{src->v} m'[src] + m'[v]) + b_g  -> BN -> relu
// ---------------------------------------------------------------------------
__global__ __launch_bounds__(256) void k_aggregate(
    const float* __restrict__ mp, const int* __restrict__ row_ptr,
    const int* __restrict__ csr, const float* __restrict__ dinv,
    const float* __restrict__ bg, const float* __restrict__ gamma,
    const float* __restrict__ beta, const float* __restrict__ mean,
    const float* __restrict__ var, float* __restrict__ hout, int N) {
  const int wave = threadIdx.x >> 6, l = threadIdx.x & 63;
  const int v = blockIdx.x * 4 + wave;
  if (v >= N) return;
  const float4* mp4 = (const float4*)mp;
  float4 acc = mp4[(size_t)v * 64 + l];  // self loop term
  const int s = row_ptr[v], e = row_ptr[v + 1];
  int i = s;
  for (; i + 4 <= e; i += 4) {
    int u0 = csr[i], u1 = csr[i + 1], u2 = csr[i + 2], u3 = csr[i + 3];
    float4 x0 = mp4[(size_t)u0 * 64 + l];
    float4 x1 = mp4[(size_t)u1 * 64 + l];
    float4 x2 = mp4[(size_t)u2 * 64 + l];
    float4 x3 = mp4[(size_t)u3 * 64 + l];
    acc.x += x0.x + x1.x + x2.x + x3.x;
    acc.y += x0.y + x1.y + x2.y + x3.y;
    acc.z += x0.z + x1.z + x2.z + x3.z;
    acc.w += x0.w + x1.w + x2.w + x3.w;
  }
  for (; i < e; ++i) {
    int u = csr[i];
    float4 x0 = mp4[(size_t)u * 64 + l];
    acc.x += x0.x;
    acc.y += x0.y;
    acc.z += x0.z;
    acc.w += x0.w;
  }
  const int c = l << 2;
  const float dv = dinv[v];
  float4 bg4 = *(const float4*)&bg[c];
  float4 g4 = *(const float4*)&gamma[c];
  float4 be4 = *(const float4*)&beta[c];
  float4 mn4 = *(const float4*)&mean[c];
  float4 vr4 = *(const float4*)&var[c];
  float4 o;
  o.x = fmaxf((acc.x * dv + bg4.x - mn4.x) * (g4.x / sqrtf(vr4.x + 1e-5f)) + be4.x, 0.f);
  o.y = fmaxf((acc.y * dv + bg4.y - mn4.y) * (g4.y / sqrtf(vr4.y + 1e-5f)) + be4.y, 0.f);
  o.z = fmaxf((acc.z * dv + bg4.z - mn4.z) * (g4.z / sqrtf(vr4.z + 1e-5f)) + be4.z, 0.f);
  o.w = fmaxf((acc.w * dv + bg4.w - mn4.w) * (g4.w / sqrtf(vr4.w + 1e-5f)) + be4.w, 0.f);
  ((float4*)hout)[(size_t)v * 64 + l] = o;
}

// ---------------------------------------------------------------------------
// Mean pool per graph (batch sorted; correctness doesn't require it)
// ---------------------------------------------------------------------------
__global__ __launch_bounds__(256) void k_count(const int* __restrict__ batch,
                                               float* __restrict__ cnt, int N) {
  int n = blockIdx.x * blockDim.x + threadIdx.x;
  if (n < N) atomicAdd(&cnt[batch[n]], 1.0f);
}

__global__ __launch_bounds__(256) void k_pool(const float* __restrict__ h,
                                              const int* __restrict__ batch,
                                              float* __restrict__ sums, int N) {
  const int t = threadIdx.x;
  const int start = blockIdx.x * 256;
  if (start >= N) return;
  const int end = min(start + 256, N);
  float acc = 0.f;
  int cur = batch[start];
  for (int n = start; n < end; ++n) {
    int g = batch[n];
    if (g != cur) {
      atomicAdd(&sums[cur * HIDDEN + t], acc);
      acc = 0.f;
      cur = g;
    }
    acc += h[(size_t)n * HIDDEN + t];
  }
  atomicAdd(&sums[cur * HIDDEN + t], acc);
}

// ---------------------------------------------------------------------------
// Head MLP: out = relu(g@W1+b1)@W2+b2, one block per graph
// ---------------------------------------------------------------------------
__global__ __launch_bounds__(128) void k_head(const float* __restrict__ sums,
                                              const float* __restrict__ cnt,
                                              const float* __restrict__ W1,
                                              const float* __restrict__ b1,
                                              const float* __restrict__ W2,
                                              const float* __restrict__ b2,
                                              float* __restrict__ out) {
  __shared__ float gr[256];
  __shared__ float t1[128];
  const int b = blockIdx.x, t = threadIdx.x;
  const float inv = 1.0f / fmaxf(cnt[b], 1.0f);
  gr[t] = sums[b * HIDDEN + t] * inv;
  gr[t + 128] = sums[b * HIDDEN + t + 128] * inv;
  __syncthreads();
  float a = b1[t];
  for (int k = 0; k < 256; ++k) a += gr[k] * W1[k * 128 + t];
  t1[t] = fmaxf(a, 0.f);
  __syncthreads();
  float o = b2[t];
  for (int k = 0; k < 128; ++k) o += t1[k] * W2[k * 128 + t];
  out[b * 128 + t] = o;
}

// ---------------------------------------------------------------------------
extern "C" void kernel_launch(void* const* d_in, const int* in_sizes, int n_in,
                              void* d_out, int out_size, void* d_ws,
                              size_t ws_size, hipStream_t stream) {
  (void)n_in;
  (void)ws_size;
  const float* x = (const float*)d_in[0];
  const int* ei = (const int*)d_in[1];
  const int* batch = (const int*)d_in[2];
  const float* W_in = (const float*)d_in[3];
  const float* b_in = (const float*)d_in[4];
  const float* W_g = (const float*)d_in[5];
  const float* b_g = (const float*)d_in[6];
  const float* bn_gamma = (const float*)d_in[7];
  const float* bn_beta = (const float*)d_in[8];
  const float* bn_mean = (const float*)d_in[9];
  const float* bn_var = (const float*)d_in[10];
  const float* W1 = (const float*)d_in[11];
  const float* b1 = (const float*)d_in[12];
  const float* W2 = (const float*)d_in[13];
  const float* b2 = (const float*)d_in[14];

  const int KIN = 768;
  const int N = in_sizes[0] / KIN;   // 100000
  const int E = in_sizes[1] / 2;     // 1600000
  const int G = out_size / 128;      // 64

  const int* src = ei;
  const int* dst = ei + E;

  char* ws = (char*)d_ws;
  size_t off = 0;
  auto take = [&](size_t bytes) -> void* {
    void* p = ws + off;
    off += (bytes + 255) & ~(size_t)255;
    return p;
  };
  const size_t S = (size_t)N * HIDDEN * sizeof(float);
  float* h0 = (float*)take(S);          // h (ping)
  float* h1 = (float*)take(S);          // m' (pong)
  float* dinv = (float*)take((size_t)N * 4);
  int* deg = (int*)take((size_t)N * 4);
  int* fill = (int*)take((size_t)N * 4);
  int* row_ptr = (int*)take((size_t)(N + 1) * 4);
  int* csr = (int*)take((size_t)E * 4);
  float* sums = (float*)take((size_t)G * HIDDEN * 4);
  float* cnt = (float*)take((size_t)G * 4);

  hipMemsetAsync(deg, 0, (size_t)N * 4, stream);
  hipMemsetAsync(fill, 0, (size_t)N * 4, stream);
  hipMemsetAsync(sums, 0, (size_t)G * HIDDEN * 4, stream);
  hipMemsetAsync(cnt, 0, (size_t)G * 4, stream);

  k_hist<<<2048, 256, 0, stream>>>(dst, deg, E);
  k_scan<<<1, 1024, 0, stream>>>(deg, row_ptr, N);
  k_dinv<<<(N + 255) / 256, 256, 0, stream>>>(deg, dinv, N);
  k_fill<<<2048, 256, 0, stream>>>(src, dst, row_ptr, fill, csr, E);

  dim3 gg((N + BM - 1) / BM, HIDDEN / BN);
  gemm256<0><<<gg, 256, 0, stream>>>(x, W_in, b_in, h0, N, KIN);
  for (int i = 0; i < 3; ++i) {
    gemm256<1><<<gg, 256, 0, stream>>>(h0, W_g + (size_t)i * HIDDEN * HIDDEN,
                                       dinv, h1, N, HIDDEN);
    k_aggregate<<<(N + 3) / 4, 256, 0, stream>>>(
        h1, row_ptr, csr, dinv, b_g + i * HIDDEN, bn_gamma + i * HIDDEN,
        bn_beta + i * HIDDEN, bn_mean + i * HIDDEN, bn_var + i * HIDDEN, h0, N);
  }
  k_count<<<(N + 255) / 256, 256, 0, stream>>>(batch, cnt, N);
  k_pool<<<(N + 255) / 256, 256, 0, stream>>>(h0, batch, sums, N);
  k_head<<<G, 128, 0, stream>>>(sums, cnt, W1, b1, W2, b2, (float*)d_out);
}

// Round 4
// 1567.845 us; speedup vs baseline: 1.7540x; 1.7540x over previous
//
#include <hip/hip_runtime.h>

#define HIDDEN 256

using bfrag = __attribute__((ext_vector_type(8))) short;   // 8 bf16 = 4 VGPRs
using facc4 = __attribute__((ext_vector_type(4))) float;   // 4 f32 accum

__device__ inline short bf16_rne(float x) {
  unsigned u = __builtin_bit_cast(unsigned, x);
  unsigned r = u + 0x7FFFu + ((u >> 16) & 1u);
  return (short)(r >> 16);
}
__device__ inline float bf16_to_f(short h) {
  unsigned u = ((unsigned)(unsigned short)h) << 16;
  return __builtin_bit_cast(float, u);
}

// ---------------------------------------------------------------------------
// CSR build: histogram over dst, exclusive scan, fill
// ---------------------------------------------------------------------------
__global__ __launch_bounds__(256) void k_hist(const int* __restrict__ dst,
                                              int* __restrict__ deg, int E) {
  for (int e = blockIdx.x * blockDim.x + threadIdx.x; e < E;
       e += gridDim.x * blockDim.x)
    atomicAdd(&deg[dst[e]], 1);
}

// 1-block scan: wave shuffle scans, 3 barriers per 1024-chunk
__global__ __launch_bounds__(1024) void k_scan(const int* __restrict__ deg,
                                               int* __restrict__ row_ptr, int N) {
  __shared__ int wsum[16];
  __shared__ int carry;
  const int t = threadIdx.x, lane = t & 63, w = t >> 6;
  if (t == 0) { carry = 0; row_ptr[0] = 0; }
  __syncthreads();
  for (int base = 0; base < N; base += 1024) {
    const int idx = base + t;
    int x = (idx < N) ? deg[idx] : 0;
#pragma unroll
    for (int off = 1; off < 64; off <<= 1) {
      int y = __shfl_up(x, off);
      if (lane >= off) x += y;
    }
    if (lane == 63) wsum[w] = x;
    __syncthreads();
    if (w == 0 && lane < 16) {
      int s = wsum[lane];
#pragma unroll
      for (int off = 1; off < 16; off <<= 1) {
        int y = __shfl_up(s, off);
        if (lane >= off) s += y;
      }
      wsum[lane] = s;
    }
    __syncthreads();
    const int total = wsum[15];
    const int inc = carry + (w > 0 ? wsum[w - 1] : 0) + x;
    if (idx < N) row_ptr[idx + 1] = inc;
    __syncthreads();
    if (t == 0) carry += total;
  }
}

__global__ __launch_bounds__(256) void k_dinv(const int* __restrict__ deg,
                                              float* __restrict__ dinv, int N) {
  int v = blockIdx.x * blockDim.x + threadIdx.x;
  if (v < N) dinv[v] = 1.0f / sqrtf((float)deg[v] + 1.0f);  // +1 self loop
}

__global__ __launch_bounds__(256) void k_fill(const int* __restrict__ src,
                                              const int* __restrict__ dst,
                                              const int* __restrict__ row_ptr,
                                              int* __restrict__ fill,
                                              int* __restrict__ csr, int E) {
  for (int e = blockIdx.x * blockDim.x + threadIdx.x; e < E;
       e += gridDim.x * blockDim.x) {
    int d = dst[e];
    int pos = atomicAdd(&fill[d], 1);
    csr[row_ptr[d] + pos] = src[e];
  }
}

// ---------------------------------------------------------------------------
// Weight prep: expand fp32 W into tiled split-bf16 layout.
// Per GEMM: tiles of 32 fp32-k: Wt[tile][n][64 shorts], row layout
// [hi k0..15][lo k0..15][hi k16..31][lo k16..31].
// Wt offsets (shorts): W_in at 0 (24 tiles), layer l at 393216 + l*131072.
// ---------------------------------------------------------------------------
__global__ __launch_bounds__(256) void k_prep_w(const float* __restrict__ W_in,
                                                const float* __restrict__ W_g,
                                                short* __restrict__ Wt) {
  const int e = blockIdx.x * blockDim.x + threadIdx.x;
  if (e >= 196608 + 3 * 65536) return;
  float v;
  int k, n;
  size_t base;
  if (e < 196608) {           // W_in [768][256]
    k = e >> 8;
    n = e & 255;
    v = W_in[e];
    base = 0;
  } else {                    // W_g [3][256][256]
    int r = e - 196608;
    int l = r >> 16;
    k = (r >> 8) & 255;
    n = r & 255;
    v = W_g[r];
    base = 393216 + (size_t)l * 131072;
  }
  size_t pos = base + (size_t)(k >> 5) * 16384 + (size_t)n * 64 +
               ((k >> 4) & 1) * 32 + (k & 15);
  short hi = bf16_rne(v);
  short lo = bf16_rne(v - bf16_to_f(hi));
  Wt[pos] = hi;
  Wt[pos + 16] = lo;
}

// ---------------------------------------------------------------------------
// Split-bf16 MFMA GEMM: C[M,256] = A[M,K] @ B[K,256] (fp32 in/out).
// BM=64, BN=256 (grid.y==1 -> A converted exactly once), BK=32 fp32.
// 256 threads = 4 waves; wave w owns cols [64w,64w+64): 4x4 frags of 16x16x32.
// Each 16-fp32-k sub-chunk -> bf16 [hi|lo] K=32 chunk; 2 MFMAs:
//   pass1: B slot g   -> ah*bh + al*bl
//   pass2: B slot g^2 -> ah*bl + al*bh
// EPI==0: C = relu(A@B + bias[256]);  EPI==1: C = rowscale[r]*(A@B)
// ---------------------------------------------------------------------------
template <int EPI>
__global__ __launch_bounds__(256) void gemm_mfma(const float* __restrict__ A,
                                                 const short* __restrict__ Wt,
                                                 const float* __restrict__ aux,
                                                 float* __restrict__ C,
                                                 int M, int K) {
  __shared__ short As[64][72];    // 64 data shorts + 8 pad
  __shared__ short Bs[256][72];
  const int t = threadIdx.x;
  const int w = t >> 6, l = t & 63;
  const int g = l >> 4, m16 = l & 15;
  const int row0 = blockIdx.x * 64;
  const int arow = t >> 2, ak = (t & 3) << 3;
  const int slotbase = ((ak >> 4) << 5) + (ak & 15);

  facc4 acc[4][4];
#pragma unroll
  for (int i = 0; i < 4; ++i)
#pragma unroll
    for (int j = 0; j < 4; ++j) acc[i][j] = (facc4)(0.0f);

  const int nsteps = K >> 5;
  for (int s = 0; s < nsteps; ++s) {
    const int k0 = s << 5;
    // --- stage A: 8 fp32 per thread -> hi/lo bf16 ---
    float av[8];
    const int ga = row0 + arow;
    if (ga < M) {
      float4 f0 = *(const float4*)&A[(size_t)ga * K + k0 + ak];
      float4 f1 = *(const float4*)&A[(size_t)ga * K + k0 + ak + 4];
      av[0] = f0.x; av[1] = f0.y; av[2] = f0.z; av[3] = f0.w;
      av[4] = f1.x; av[5] = f1.y; av[6] = f1.z; av[7] = f1.w;
    } else {
#pragma unroll
      for (int i = 0; i < 8; ++i) av[i] = 0.f;
    }
    bfrag hi, lo;
#pragma unroll
    for (int i = 0; i < 8; ++i) {
      short h = bf16_rne(av[i]);
      hi[i] = h;
      lo[i] = bf16_rne(av[i] - bf16_to_f(h));
    }
    // --- stage B: flat copy of precomputed 32KB tile, row n = t ---
    const short* wbase = Wt + ((size_t)s << 14) + (t << 6);
    bfrag bstage[8];
#pragma unroll
    for (int j = 0; j < 8; ++j) bstage[j] = *(const bfrag*)(wbase + (j << 3));
    __syncthreads();
    *(bfrag*)&As[arow][slotbase] = hi;
    *(bfrag*)&As[arow][slotbase + 16] = lo;
#pragma unroll
    for (int j = 0; j < 8; ++j) *(bfrag*)&Bs[t][j << 3] = bstage[j];
    __syncthreads();
    // --- compute ---
#pragma unroll
    for (int c = 0; c < 2; ++c) {
      bfrag a[4], b1[4], b2[4];
#pragma unroll
      for (int mf = 0; mf < 4; ++mf)
        a[mf] = *(const bfrag*)&As[mf * 16 + m16][c * 32 + g * 8];
#pragma unroll
      for (int nf = 0; nf < 4; ++nf) {
        const short* bp = &Bs[w * 64 + nf * 16 + m16][c * 32];
        b1[nf] = *(const bfrag*)(bp + g * 8);
        b2[nf] = *(const bfrag*)(bp + ((g ^ 2) * 8));
      }
#pragma unroll
      for (int mf = 0; mf < 4; ++mf)
#pragma unroll
        for (int nf = 0; nf < 4; ++nf) {
          acc[mf][nf] = __builtin_amdgcn_mfma_f32_16x16x32_bf16(
              a[mf], b1[nf], acc[mf][nf], 0, 0, 0);
          acc[mf][nf] = __builtin_amdgcn_mfma_f32_16x16x32_bf16(
              a[mf], b2[nf], acc[mf][nf], 0, 0, 0);
        }
    }
  }
  // --- epilogue: D layout col=lane&15, row=(lane>>4)*4+reg ---
  const int colbase = w * 64;
  if (EPI == 0) {
#pragma unroll
    for (int nf = 0; nf < 4; ++nf) {
      const float bias = aux[colbase + nf * 16 + m16];
#pragma unroll
      for (int mf = 0; mf < 4; ++mf)
#pragma unroll
        for (int r = 0; r < 4; ++r) {
          int row = row0 + mf * 16 + g * 4 + r;
          if (row < M)
            C[(size_t)row * HIDDEN + colbase + nf * 16 + m16] =
                fmaxf(acc[mf][nf][r] + bias, 0.f);
        }
    }
  } else {
#pragma unroll
    for (int mf = 0; mf < 4; ++mf)
#pragma unroll
      for (int r = 0; r < 4; ++r) {
        int row = row0 + mf * 16 + g * 4 + r;
        if (row >= M) continue;
        const float sc = aux[row];
#pragma unroll
        for (int nf = 0; nf < 4; ++nf)
          C[(size_t)row * HIDDEN + colbase + nf * 16 + m16] =
              acc[mf][nf][r] * sc;
      }
  }
}

// ---------------------------------------------------------------------------
// Gather aggregation + bias + BN + ReLU. One wave per node; lane = float4 slice.
// ---------------------------------------------------------------------------
__global__ __launch_bounds__(256) void k_aggregate(
    const float* __restrict__ mp, const int* __restrict__ row_ptr,
    const int* __restrict__ csr, const float* __restrict__ dinv,
    const float* __restrict__ bg, const float* __restrict__ gamma,
    const float* __restrict__ beta, const float* __restrict__ mean,
    const float* __restrict__ var, float* __restrict__ hout, int N) {
  const int wave = threadIdx.x >> 6, l = threadIdx.x & 63;
  const int v = blockIdx.x * 4 + wave;
  if (v >= N) return;
  const float4* mp4 = (const float4*)mp;
  float4 acc = mp4[(size_t)v * 64 + l];  // self loop term
  const int s = row_ptr[v], e = row_ptr[v + 1];
  int i = s;
  for (; i + 4 <= e; i += 4) {
    int u0 = csr[i], u1 = csr[i + 1], u2 = csr[i + 2], u3 = csr[i + 3];
    float4 x0 = mp4[(size_t)u0 * 64 + l];
    float4 x1 = mp4[(size_t)u1 * 64 + l];
    float4 x2 = mp4[(size_t)u2 * 64 + l];
    float4 x3 = mp4[(size_t)u3 * 64 + l];
    acc.x += x0.x + x1.x + x2.x + x3.x;
    acc.y += x0.y + x1.y + x2.y + x3.y;
    acc.z += x0.z + x1.z + x2.z + x3.z;
    acc.w += x0.w + x1.w + x2.w + x3.w;
  }
  for (; i < e; ++i) {
    int u = csr[i];
    float4 x0 = mp4[(size_t)u * 64 + l];
    acc.x += x0.x;
    acc.y += x0.y;
    acc.z += x0.z;
    acc.w += x0.w;
  }
  const int c = l << 2;
  const float dv = dinv[v];
  float4 bg4 = *(const float4*)&bg[c];
  float4 g4 = *(const float4*)&gamma[c];
  float4 be4 = *(const float4*)&beta[c];
  float4 mn4 = *(const float4*)&mean[c];
  float4 vr4 = *(const float4*)&var[c];
  float4 o;
  o.x = fmaxf((acc.x * dv + bg4.x - mn4.x) * (g4.x / sqrtf(vr4.x + 1e-5f)) + be4.x, 0.f);
  o.y = fmaxf((acc.y * dv + bg4.y - mn4.y) * (g4.y / sqrtf(vr4.y + 1e-5f)) + be4.y, 0.f);
  o.z = fmaxf((acc.z * dv + bg4.z - mn4.z) * (g4.z / sqrtf(vr4.z + 1e-5f)) + be4.z, 0.f);
  o.w = fmaxf((acc.w * dv + bg4.w - mn4.w) * (g4.w / sqrtf(vr4.w + 1e-5f)) + be4.w, 0.f);
  ((float4*)hout)[(size_t)v * 64 + l] = o;
}

// ---------------------------------------------------------------------------
// Counts via binary search (batch is sorted by construction: jnp.sort)
// ---------------------------------------------------------------------------
__global__ __launch_bounds__(64) void k_count(const int* __restrict__ batch,
                                              float* __restrict__ cnt, int N,
                                              int G) {
  const int g = threadIdx.x;
  if (g >= G) return;
  int lo = 0, hi = N;
  while (lo < hi) {
    int mid = (lo + hi) >> 1;
    if (batch[mid] < g) lo = mid + 1; else hi = mid;
  }
  int lo2 = lo, hi2 = N;
  while (lo2 < hi2) {
    int mid = (lo2 + hi2) >> 1;
    if (batch[mid] < g + 1) lo2 = mid + 1; else hi2 = mid;
  }
  cnt[g] = (float)(lo2 - lo);
}

__global__ __launch_bounds__(256) void k_pool(const float* __restrict__ h,
                                              const int* __restrict__ batch,
                                              float* __restrict__ sums, int N) {
  const int t = threadIdx.x;
  const int start = blockIdx.x * 256;
  if (start >= N) return;
  const int end = min(start + 256, N);
  float acc = 0.f;
  int cur = batch[start];
  for (int n = start; n < end; ++n) {
    int g = batch[n];
    if (g != cur) {
      atomicAdd(&sums[cur * HIDDEN + t], acc);
      acc = 0.f;
      cur = g;
    }
    acc += h[(size_t)n * HIDDEN + t];
  }
  atomicAdd(&sums[cur * HIDDEN + t], acc);
}

// ---------------------------------------------------------------------------
// Head MLP: out = relu(g@W1+b1)@W2+b2, one block per graph
// ---------------------------------------------------------------------------
__global__ __launch_bounds__(128) void k_head(const float* __restrict__ sums,
                                              const float* __restrict__ cnt,
                                              const float* __restrict__ W1,
                                              const float* __restrict__ b1,
                                              const float* __restrict__ W2,
                                              const float* __restrict__ b2,
                                              float* __restrict__ out) {
  __shared__ float gr[256];
  __shared__ float t1[128];
  const int b = blockIdx.x, t = threadIdx.x;
  const float inv = 1.0f / fmaxf(cnt[b], 1.0f);
  gr[t] = sums[b * HIDDEN + t] * inv;
  gr[t + 128] = sums[b * HIDDEN + t + 128] * inv;
  __syncthreads();
  float a = b1[t];
  for (int k = 0; k < 256; ++k) a += gr[k] * W1[k * 128 + t];
  t1[t] = fmaxf(a, 0.f);
  __syncthreads();
  float o = b2[t];
  for (int k = 0; k < 128; ++k) o += t1[k] * W2[k * 128 + t];
  out[b * 128 + t] = o;
}

// ---------------------------------------------------------------------------
extern "C" void kernel_launch(void* const* d_in, const int* in_sizes, int n_in,
                              void* d_out, int out_size, void* d_ws,
                              size_t ws_size, hipStream_t stream) {
  (void)n_in;
  (void)ws_size;
  const float* x = (const float*)d_in[0];
  const int* ei = (const int*)d_in[1];
  const int* batch = (const int*)d_in[2];
  const float* W_in = (const float*)d_in[3];
  const float* b_in = (const float*)d_in[4];
  const float* W_g = (const float*)d_in[5];
  const float* b_g = (const float*)d_in[6];
  const float* bn_gamma = (const float*)d_in[7];
  const float* bn_beta = (const float*)d_in[8];
  const float* bn_mean = (const float*)d_in[9];
  const float* bn_var = (const float*)d_in[10];
  const float* W1 = (const float*)d_in[11];
  const float* b1 = (const float*)d_in[12];
  const float* W2 = (const float*)d_in[13];
  const float* b2 = (const float*)d_in[14];

  const int KIN = 768;
  const int N = in_sizes[0] / KIN;   // 100000
  const int E = in_sizes[1] / 2;     // 1600000
  const int G = out_size / 128;      // 64

  const int* src = ei;
  const int* dst = ei + E;

  char* ws = (char*)d_ws;
  size_t off = 0;
  auto take = [&](size_t bytes) -> void* {
    void* p = ws + off;
    off += (bytes + 255) & ~(size_t)255;
    return p;
  };
  const size_t S = (size_t)N * HIDDEN * sizeof(float);
  float* h0 = (float*)take(S);
  float* h1 = (float*)take(S);
  float* dinv = (float*)take((size_t)N * 4);
  int* deg = (int*)take((size_t)N * 4);
  int* fill = (int*)take((size_t)N * 4);
  int* row_ptr = (int*)take((size_t)(N + 1) * 4);
  int* csr = (int*)take((size_t)E * 4);
  float* sums = (float*)take((size_t)G * HIDDEN * 4);
  float* cnt = (float*)take((size_t)G * 4);
  short* Wt = (short*)take((size_t)(393216 + 3 * 131072) * 2);

  hipMemsetAsync(deg, 0, (size_t)N * 4, stream);
  hipMemsetAsync(fill, 0, (size_t)N * 4, stream);
  hipMemsetAsync(sums, 0, (size_t)G * HIDDEN * 4, stream);

  k_prep_w<<<(196608 + 3 * 65536 + 255) / 256, 256, 0, stream>>>(W_in, W_g, Wt);
  k_hist<<<2048, 256, 0, stream>>>(dst, deg, E);
  k_scan<<<1, 1024, 0, stream>>>(deg, row_ptr, N);
  k_dinv<<<(N + 255) / 256, 256, 0, stream>>>(deg, dinv, N);
  k_fill<<<2048, 256, 0, stream>>>(src, dst, row_ptr, fill, csr, E);

  const int gx = (N + 63) / 64;
  gemm_mfma<0><<<gx, 256, 0, stream>>>(x, Wt, b_in, h0, N, KIN);
  for (int i = 0; i < 3; ++i) {
    gemm_mfma<1><<<gx, 256, 0, stream>>>(h0, Wt + 393216 + (size_t)i * 131072,
                                         dinv, h1, N, HIDDEN);
    k_aggregate<<<(N + 3) / 4, 256, 0, stream>>>(
        h1, row_ptr, csr, dinv, b_g + i * HIDDEN, bn_gamma + i * HIDDEN,
        bn_beta + i * HIDDEN, bn_mean + i * HIDDEN, bn_var + i * HIDDEN, h0, N);
  }
  k_count<<<1, 64, 0, stream>>>(batch, cnt, N, G);
  k_pool<<<(N + 255) / 256, 256, 0, stream>>>(h0, batch, sums, N);
  k_head<<<G, 128, 0, stream>>>(sums, cnt, W1, b1, W2, b2, (float*)d_out);
}

// Round 5
// 1461.157 us; speedup vs baseline: 1.8820x; 1.0730x over previous
//
#include <hip/hip_runtime.h>

#define HIDDEN 256

using bfrag = __attribute__((ext_vector_type(8))) short;   // 8 bf16 = 4 VGPRs
using facc4 = __attribute__((ext_vector_type(4))) float;   // 4 f32 accum

__device__ inline short bf16_rne(float x) {
  unsigned u = __builtin_bit_cast(unsigned, x);
  unsigned r = u + 0x7FFFu + ((u >> 16) & 1u);
  return (short)(r >> 16);
}
__device__ inline float bf16_to_f(short h) {
  unsigned u = ((unsigned)(unsigned short)h) << 16;
  return __builtin_bit_cast(float, u);
}

// ---------------------------------------------------------------------------
// CSR build: histogram over dst, exclusive scan, fill
// ---------------------------------------------------------------------------
__global__ __launch_bounds__(256) void k_hist(const int* __restrict__ dst,
                                              int* __restrict__ deg, int E) {
  for (int e = blockIdx.x * blockDim.x + threadIdx.x; e < E;
       e += gridDim.x * blockDim.x)
    atomicAdd(&deg[dst[e]], 1);
}

// 1-block scan: wave shuffle scans, 3 barriers per 1024-chunk
__global__ __launch_bounds__(1024) void k_scan(const int* __restrict__ deg,
                                               int* __restrict__ row_ptr, int N) {
  __shared__ int wsum[16];
  __shared__ int carry;
  const int t = threadIdx.x, lane = t & 63, w = t >> 6;
  if (t == 0) { carry = 0; row_ptr[0] = 0; }
  __syncthreads();
  for (int base = 0; base < N; base += 1024) {
    const int idx = base + t;
    int x = (idx < N) ? deg[idx] : 0;
#pragma unroll
    for (int off = 1; off < 64; off <<= 1) {
      int y = __shfl_up(x, off);
      if (lane >= off) x += y;
    }
    if (lane == 63) wsum[w] = x;
    __syncthreads();
    if (w == 0 && lane < 16) {
      int s = wsum[lane];
#pragma unroll
      for (int off = 1; off < 16; off <<= 1) {
        int y = __shfl_up(s, off);
        if (lane >= off) s += y;
      }
      wsum[lane] = s;
    }
    __syncthreads();
    const int total = wsum[15];
    const int inc = carry + (w > 0 ? wsum[w - 1] : 0) + x;
    if (idx < N) row_ptr[idx + 1] = inc;
    __syncthreads();
    if (t == 0) carry += total;
  }
}

__global__ __launch_bounds__(256) void k_dinv(const int* __restrict__ deg,
                                              float* __restrict__ dinv, int N) {
  int v = blockIdx.x * blockDim.x + threadIdx.x;
  if (v < N) dinv[v] = 1.0f / sqrtf((float)deg[v] + 1.0f);  // +1 self loop
}

__global__ __launch_bounds__(256) void k_fill(const int* __restrict__ src,
                                              const int* __restrict__ dst,
                                              const int* __restrict__ row_ptr,
                                              int* __restrict__ fill,
                                              int* __restrict__ csr, int E) {
  for (int e = blockIdx.x * blockDim.x + threadIdx.x; e < E;
       e += gridDim.x * blockDim.x) {
    int d = dst[e];
    int pos = atomicAdd(&fill[d], 1);
    csr[row_ptr[d] + pos] = src[e];
  }
}

// ---------------------------------------------------------------------------
// Weight prep: expand fp32 W into split-bf16, hi/lo-separated K-tile layout.
// Per 32-k tile: [hi: n=0..255 x kk=0..31 (8192 sh)][lo: 8192 sh] = 16384 sh.
// Wt offsets (shorts): W_in at 0 (24 tiles), layer l at 393216 + l*131072.
// ---------------------------------------------------------------------------
__global__ __launch_bounds__(256) void k_prep_w(const float* __restrict__ W_in,
                                                const float* __restrict__ W_g,
                                                short* __restrict__ Wt) {
  const int e = blockIdx.x * blockDim.x + threadIdx.x;
  if (e >= 196608 + 3 * 65536) return;
  float v;
  int k, n;
  size_t base;
  if (e < 196608) {           // W_in [768][256]
    k = e >> 8;
    n = e & 255;
    v = W_in[e];
    base = 0;
  } else {                    // W_g [3][256][256]
    int r = e - 196608;
    int lyr = r >> 16;
    k = (r >> 8) & 255;
    n = r & 255;
    v = W_g[r];
    base = 393216 + (size_t)lyr * 131072;
  }
  size_t pos = base + (size_t)(k >> 5) * 16384 + (size_t)n * 32 + (k & 31);
  short hi = bf16_rne(v);
  short lo = bf16_rne(v - bf16_to_f(hi));
  Wt[pos] = hi;
  Wt[pos + 8192] = lo;
}

// ---------------------------------------------------------------------------
// Split-bf16 MFMA GEMM v2: C[M,256] = A[M,K] @ B[K,256] (fp32 in/out).
// BM=64, BN=256, BK=32 fp32. 256 threads = 4 waves; wave w owns cols
// [64w,64w+64): 4x4 frags of 16x16x32.
// Pipeline: As double-buffered (2x9KB), ONE barrier per K-step; next A tile
// prefetched to regs during compute; B fragments loaded straight from the
// hi/lo-separated Wt (L2-hot, wave-coalesced) -- no B LDS at all.
// 3 MFMAs per 32k: ah*bh + al*bh + ah*bl (al*bl term ~2^-17, dropped).
// EPI==0: C = relu(A@B + bias[256]);  EPI==1: C = rowscale[r]*(A@B)
// ---------------------------------------------------------------------------
template <int EPI>
__global__ __launch_bounds__(256) void gemm_mfma(const float* __restrict__ A,
                                                 const short* __restrict__ Wt,
                                                 const float* __restrict__ aux,
                                                 float* __restrict__ C,
                                                 int M, int K) {
  __shared__ short As[2][64][72];   // 64 data shorts ([hi k0..31|lo k0..31]) + 8 pad
  const int t = threadIdx.x;
  const int w = t >> 6, l = t & 63;
  const int g = l >> 4, m16 = l & 15;
  const int row0 = blockIdx.x * 64;
  const int arow = t >> 2, ak = (t & 3) << 3;

  facc4 acc[4][4];
#pragma unroll
  for (int i = 0; i < 4; ++i)
#pragma unroll
    for (int j = 0; j < 4; ++j) acc[i][j] = (facc4)(0.0f);

  const int nsteps = K >> 5;
  const int ga = row0 + arow;
  const bool aval = ga < M;
  const float* aptr = A + (size_t)ga * K + ak;

  float4 f0 = make_float4(0.f, 0.f, 0.f, 0.f), f1 = f0;
  if (aval) {
    f0 = *(const float4*)(aptr);
    f1 = *(const float4*)(aptr + 4);
  }

  int cur = 0;
  for (int s = 0; s < nsteps; ++s) {
    // --- convert tile s (truncation split: hi trunc, lo = trunc(a - hi)) ---
    float av[8] = {f0.x, f0.y, f0.z, f0.w, f1.x, f1.y, f1.z, f1.w};
    bfrag hif, lof;
#pragma unroll
    for (int i = 0; i < 8; ++i) {
      unsigned u = __builtin_bit_cast(unsigned, av[i]);
      hif[i] = (short)(u >> 16);
      float r = av[i] - __builtin_bit_cast(float, u & 0xFFFF0000u);
      lof[i] = (short)(__builtin_bit_cast(unsigned, r) >> 16);
    }
    *(bfrag*)&As[cur][arow][ak] = hif;
    *(bfrag*)&As[cur][arow][32 + ak] = lof;
    // --- prefetch tile s+1 (in flight across the whole compute phase) ---
    if (s + 1 < nsteps && aval) {
      f0 = *(const float4*)(aptr + (size_t)(s + 1) * 32);
      f1 = *(const float4*)(aptr + (size_t)(s + 1) * 32 + 4);
    }
    __syncthreads();
    // --- B fragments straight from global (L2-hot weights) ---
    const short* wb = Wt + ((size_t)s << 14) + (size_t)(w * 64 + m16) * 32 + g * 8;
    bfrag bh[4], bl[4];
#pragma unroll
    for (int nf = 0; nf < 4; ++nf) {
      bh[nf] = *(const bfrag*)(wb + nf * 512);
      bl[nf] = *(const bfrag*)(wb + nf * 512 + 8192);
    }
    // --- A fragments from LDS ---
    bfrag ah[4], al[4];
#pragma unroll
    for (int mf = 0; mf < 4; ++mf) {
      ah[mf] = *(const bfrag*)&As[cur][mf * 16 + m16][g * 8];
      al[mf] = *(const bfrag*)&As[cur][mf * 16 + m16][32 + g * 8];
    }
    // --- 48 MFMAs, same-acc chains spaced 16 apart ---
#pragma unroll
    for (int nf = 0; nf < 4; ++nf)
#pragma unroll
      for (int mf = 0; mf < 4; ++mf)
        acc[mf][nf] = __builtin_amdgcn_mfma_f32_16x16x32_bf16(
            ah[mf], bh[nf], acc[mf][nf], 0, 0, 0);
#pragma unroll
    for (int nf = 0; nf < 4; ++nf)
#pragma unroll
      for (int mf = 0; mf < 4; ++mf)
        acc[mf][nf] = __builtin_amdgcn_mfma_f32_16x16x32_bf16(
            al[mf], bh[nf], acc[mf][nf], 0, 0, 0);
#pragma unroll
    for (int nf = 0; nf < 4; ++nf)
#pragma unroll
      for (int mf = 0; mf < 4; ++mf)
        acc[mf][nf] = __builtin_amdgcn_mfma_f32_16x16x32_bf16(
            ah[mf], bl[nf], acc[mf][nf], 0, 0, 0);
    cur ^= 1;
  }
  // --- epilogue: D layout col=lane&15, row=(lane>>4)*4+reg ---
  const int colbase = w * 64;
  if (EPI == 0) {
#pragma unroll
    for (int nf = 0; nf < 4; ++nf) {
      const float bias = aux[colbase + nf * 16 + m16];
#pragma unroll
      for (int mf = 0; mf < 4; ++mf)
#pragma unroll
        for (int r = 0; r < 4; ++r) {
          int row = row0 + mf * 16 + g * 4 + r;
          if (row < M)
            C[(size_t)row * HIDDEN + colbase + nf * 16 + m16] =
                fmaxf(acc[mf][nf][r] + bias, 0.f);
        }
    }
  } else {
#pragma unroll
    for (int mf = 0; mf < 4; ++mf)
#pragma unroll
      for (int r = 0; r < 4; ++r) {
        int row = row0 + mf * 16 + g * 4 + r;
        if (row >= M) continue;
        const float sc = aux[row];
#pragma unroll
        for (int nf = 0; nf < 4; ++nf)
          C[(size_t)row * HIDDEN + colbase + nf * 16 + m16] =
              acc[mf][nf][r] * sc;
      }
  }
}

// ---------------------------------------------------------------------------
// Gather aggregation + bias + BN + ReLU. One wave per node; lane = float4 slice.
// ---------------------------------------------------------------------------
__global__ __launch_bounds__(256) void k_aggregate(
    const float* __restrict__ mp, const int* __restrict__ row_ptr,
    const int* __restrict__ csr, const float* __restrict__ dinv,
    const float* __restrict__ bg, const float* __restrict__ gamma,
    const float* __restrict__ beta, const float* __restrict__ mean,
    const float* __restrict__ var, float* __restrict__ hout, int N) {
  const int wave = threadIdx.x >> 6, l = threadIdx.x & 63;
  const int v = blockIdx.x * 4 + wave;
  if (v >= N) return;
  const float4* mp4 = (const float4*)mp;
  float4 acc = mp4[(size_t)v * 64 + l];  // self loop term
  const int s = row_ptr[v], e = row_ptr[v + 1];
  int i = s;
  for (; i + 4 <= e; i += 4) {
    int u0 = csr[i], u1 = csr[i + 1], u2 = csr[i + 2], u3 = csr[i + 3];
    float4 x0 = mp4[(size_t)u0 * 64 + l];
    float4 x1 = mp4[(size_t)u1 * 64 + l];
    float4 x2 = mp4[(size_t)u2 * 64 + l];
    float4 x3 = mp4[(size_t)u3 * 64 + l];
    acc.x += x0.x + x1.x + x2.x + x3.x;
    acc.y += x0.y + x1.y + x2.y + x3.y;
    acc.z += x0.z + x1.z + x2.z + x3.z;
    acc.w += x0.w + x1.w + x2.w + x3.w;
  }
  for (; i < e; ++i) {
    int u = csr[i];
    float4 x0 = mp4[(size_t)u * 64 + l];
    acc.x += x0.x;
    acc.y += x0.y;
    acc.z += x0.z;
    acc.w += x0.w;
  }
  const int c = l << 2;
  const float dv = dinv[v];
  float4 bg4 = *(const float4*)&bg[c];
  float4 g4 = *(const float4*)&gamma[c];
  float4 be4 = *(const float4*)&beta[c];
  float4 mn4 = *(const float4*)&mean[c];
  float4 vr4 = *(const float4*)&var[c];
  float4 o;
  o.x = fmaxf((acc.x * dv + bg4.x - mn4.x) * (g4.x / sqrtf(vr4.x + 1e-5f)) + be4.x, 0.f);
  o.y = fmaxf((acc.y * dv + bg4.y - mn4.y) * (g4.y / sqrtf(vr4.y + 1e-5f)) + be4.y, 0.f);
  o.z = fmaxf((acc.z * dv + bg4.z - mn4.z) * (g4.z / sqrtf(vr4.z + 1e-5f)) + be4.z, 0.f);
  o.w = fmaxf((acc.w * dv + bg4.w - mn4.w) * (g4.w / sqrtf(vr4.w + 1e-5f)) + be4.w, 0.f);
  ((float4*)hout)[(size_t)v * 64 + l] = o;
}

// ---------------------------------------------------------------------------
// Counts via binary search (batch is sorted by construction: jnp.sort)
// ---------------------------------------------------------------------------
__global__ __launch_bounds__(64) void k_count(const int* __restrict__ batch,
                                              float* __restrict__ cnt, int N,
                                              int G) {
  const int g = threadIdx.x;
  if (g >= G) return;
  int lo = 0, hi = N;
  while (lo < hi) {
    int mid = (lo + hi) >> 1;
    if (batch[mid] < g) lo = mid + 1; else hi = mid;
  }
  int lo2 = lo, hi2 = N;
  while (lo2 < hi2) {
    int mid = (lo2 + hi2) >> 1;
    if (batch[mid] < g + 1) lo2 = mid + 1; else hi2 = mid;
  }
  cnt[g] = (float)(lo2 - lo);
}

__global__ __launch_bounds__(256) void k_pool(const float* __restrict__ h,
                                              const int* __restrict__ batch,
                                              float* __restrict__ sums, int N) {
  const int t = threadIdx.x;
  const int start = blockIdx.x * 256;
  if (start >= N) return;
  const int end = min(start + 256, N);
  float acc = 0.f;
  int cur = batch[start];
  for (int n = start; n < end; ++n) {
    int g = batch[n];
    if (g != cur) {
      atomicAdd(&sums[cur * HIDDEN + t], acc);
      acc = 0.f;
      cur = g;
    }
    acc += h[(size_t)n * HIDDEN + t];
  }
  atomicAdd(&sums[cur * HIDDEN + t], acc);
}

// ---------------------------------------------------------------------------
// Head MLP: out = relu(g@W1+b1)@W2+b2, one block per graph
// ---------------------------------------------------------------------------
__global__ __launch_bounds__(128) void k_head(const float* __restrict__ sums,
                                              const float* __restrict__ cnt,
                                              const float* __restrict__ W1,
                                              const float* __restrict__ b1,
                                              const float* __restrict__ W2,
                                              const float* __restrict__ b2,
                                              float* __restrict__ out) {
  __shared__ float gr[256];
  __shared__ float t1[128];
  const int b = blockIdx.x, t = threadIdx.x;
  const float inv = 1.0f / fmaxf(cnt[b], 1.0f);
  gr[t] = sums[b * HIDDEN + t] * inv;
  gr[t + 128] = sums[b * HIDDEN + t + 128] * inv;
  __syncthreads();
  float a = b1[t];
  for (int k = 0; k < 256; ++k) a += gr[k] * W1[k * 128 + t];
  t1[t] = fmaxf(a, 0.f);
  __syncthreads();
  float o = b2[t];
  for (int k = 0; k < 128; ++k) o += t1[k] * W2[k * 128 + t];
  out[b * 128 + t] = o;
}

// ---------------------------------------------------------------------------
extern "C" void kernel_launch(void* const* d_in, const int* in_sizes, int n_in,
                              void* d_out, int out_size, void* d_ws,
                              size_t ws_size, hipStream_t stream) {
  (void)n_in;
  (void)ws_size;
  const float* x = (const float*)d_in[0];
  const int* ei = (const int*)d_in[1];
  const int* batch = (const int*)d_in[2];
  const float* W_in = (const float*)d_in[3];
  const float* b_in = (const float*)d_in[4];
  const float* W_g = (const float*)d_in[5];
  const float* b_g = (const float*)d_in[6];
  const float* bn_gamma = (const float*)d_in[7];
  const float* bn_beta = (const float*)d_in[8];
  const float* bn_mean = (const float*)d_in[9];
  const float* bn_var = (const float*)d_in[10];
  const float* W1 = (const float*)d_in[11];
  const float* b1 = (const float*)d_in[12];
  const float* W2 = (const float*)d_in[13];
  const float* b2 = (const float*)d_in[14];

  const int KIN = 768;
  const int N = in_sizes[0] / KIN;   // 100000
  const int E = in_sizes[1] / 2;     // 1600000
  const int G = out_size / 128;      // 64

  const int* src = ei;
  const int* dst = ei + E;

  char* ws = (char*)d_ws;
  size_t off = 0;
  auto take = [&](size_t bytes) -> void* {
    void* p = ws + off;
    off += (bytes + 255) & ~(size_t)255;
    return p;
  };
  const size_t S = (size_t)N * HIDDEN * sizeof(float);
  float* h0 = (float*)take(S);
  float* h1 = (float*)take(S);
  float* dinv = (float*)take((size_t)N * 4);
  int* deg = (int*)take((size_t)N * 4);
  int* fill = (int*)take((size_t)N * 4);
  int* row_ptr = (int*)take((size_t)(N + 1) * 4);
  int* csr = (int*)take((size_t)E * 4);
  float* sums = (float*)take((size_t)G * HIDDEN * 4);
  float* cnt = (float*)take((size_t)G * 4);
  short* Wt = (short*)take((size_t)(393216 + 3 * 131072) * 2);

  hipMemsetAsync(deg, 0, (size_t)N * 4, stream);
  hipMemsetAsync(fill, 0, (size_t)N * 4, stream);
  hipMemsetAsync(sums, 0, (size_t)G * HIDDEN * 4, stream);

  k_prep_w<<<(196608 + 3 * 65536 + 255) / 256, 256, 0, stream>>>(W_in, W_g, Wt);
  k_hist<<<2048, 256, 0, stream>>>(dst, deg, E);
  k_scan<<<1, 1024, 0, stream>>>(deg, row_ptr, N);
  k_dinv<<<(N + 255) / 256, 256, 0, stream>>>(deg, dinv, N);
  k_fill<<<2048, 256, 0, stream>>>(src, dst, row_ptr, fill, csr, E);

  const int gx = (N + 63) / 64;
  gemm_mfma<0><<<gx, 256, 0, stream>>>(x, Wt, b_in, h0, N, KIN);
  for (int i = 0; i < 3; ++i) {
    gemm_mfma<1><<<gx, 256, 0, stream>>>(h0, Wt + 393216 + (size_t)i * 131072,
                                         dinv, h1, N, HIDDEN);
    k_aggregate<<<(N + 3) / 4, 256, 0, stream>>>(
        h1, row_ptr, csr, dinv, b_g + i * HIDDEN, bn_gamma + i * HIDDEN,
        bn_beta + i * HIDDEN, bn_mean + i * HIDDEN, bn_var + i * HIDDEN, h0, N);
  }
  k_count<<<1, 64, 0, stream>>>(batch, cnt, N, G);
  k_pool<<<(N + 255) / 256, 256, 0, stream>>>(h0, batch, sums, N);
  k_head<<<G, 128, 0, stream>>>(sums, cnt, W1, b1, W2, b2, (float*)d_out);
}

// Round 6
// 1105.113 us; speedup vs baseline: 2.4884x; 1.3222x over previous
//
#include <hip/hip_runtime.h>
#include <hip/hip_fp16.h>

#define HIDDEN 256

using bfrag = __attribute__((ext_vector_type(8))) short;   // 8 bf16 = 4 VGPRs
using facc4 = __attribute__((ext_vector_type(4))) float;   // 4 f32 accum

__device__ inline short bf16_rne(float x) {
  unsigned u = __builtin_bit_cast(unsigned, x);
  unsigned r = u + 0x7FFFu + ((u >> 16) & 1u);
  return (short)(r >> 16);
}
__device__ inline float bf16_to_f(short h) {
  unsigned u = ((unsigned)(unsigned short)h) << 16;
  return __builtin_bit_cast(float, u);
}
__device__ inline float h2f(unsigned short h) {
  return __half2float(__builtin_bit_cast(__half, h));
}

// ---------------------------------------------------------------------------
// CSR build: histogram over dst, exclusive scan, fill
// ---------------------------------------------------------------------------
__global__ __launch_bounds__(256) void k_hist(const int* __restrict__ dst,
                                              int* __restrict__ deg, int E) {
  for (int e = blockIdx.x * blockDim.x + threadIdx.x; e < E;
       e += gridDim.x * blockDim.x)
    atomicAdd(&deg[dst[e]], 1);
}

// 1-block scan: wave shuffle scans, 3 barriers per 1024-chunk
__global__ __launch_bounds__(1024) void k_scan(const int* __restrict__ deg,
                                               int* __restrict__ row_ptr, int N) {
  __shared__ int wsum[16];
  __shared__ int carry;
  const int t = threadIdx.x, lane = t & 63, w = t >> 6;
  if (t == 0) { carry = 0; row_ptr[0] = 0; }
  __syncthreads();
  for (int base = 0; base < N; base += 1024) {
    const int idx = base + t;
    int x = (idx < N) ? deg[idx] : 0;
#pragma unroll
    for (int off = 1; off < 64; off <<= 1) {
      int y = __shfl_up(x, off);
      if (lane >= off) x += y;
    }
    if (lane == 63) wsum[w] = x;
    __syncthreads();
    if (w == 0 && lane < 16) {
      int s = wsum[lane];
#pragma unroll
      for (int off = 1; off < 16; off <<= 1) {
        int y = __shfl_up(s, off);
        if (lane >= off) s += y;
      }
      wsum[lane] = s;
    }
    __syncthreads();
    const int total = wsum[15];
    const int inc = carry + (w > 0 ? wsum[w - 1] : 0) + x;
    if (idx < N) row_ptr[idx + 1] = inc;
    __syncthreads();
    if (t == 0) carry += total;
  }
}

__global__ __launch_bounds__(256) void k_dinv(const int* __restrict__ deg,
                                              float* __restrict__ dinv, int N) {
  int v = blockIdx.x * blockDim.x + threadIdx.x;
  if (v < N) dinv[v] = 1.0f / sqrtf((float)deg[v] + 1.0f);  // +1 self loop
}

__global__ __launch_bounds__(256) void k_fill(const int* __restrict__ src,
                                              const int* __restrict__ dst,
                                              const int* __restrict__ row_ptr,
                                              int* __restrict__ fill,
                                              int* __restrict__ csr, int E) {
  for (int e = blockIdx.x * blockDim.x + threadIdx.x; e < E;
       e += gridDim.x * blockDim.x) {
    int d = dst[e];
    int pos = atomicAdd(&fill[d], 1);
    csr[row_ptr[d] + pos] = src[e];
  }
}

// ---------------------------------------------------------------------------
// Weight prep: expand fp32 W into split-bf16, hi/lo-separated K-tile layout.
// Per 32-k tile: [hi: n=0..255 x kk=0..31 (8192 sh)][lo: 8192 sh] = 16384 sh.
// Wt offsets (shorts): W_in at 0 (24 tiles), layer l at 393216 + l*131072.
// ---------------------------------------------------------------------------
__global__ __launch_bounds__(256) void k_prep_w(const float* __restrict__ W_in,
                                                const float* __restrict__ W_g,
                                                short* __restrict__ Wt) {
  const int e = blockIdx.x * blockDim.x + threadIdx.x;
  if (e >= 196608 + 3 * 65536) return;
  float v;
  int k, n;
  size_t base;
  if (e < 196608) {           // W_in [768][256]
    k = e >> 8;
    n = e & 255;
    v = W_in[e];
    base = 0;
  } else {                    // W_g [3][256][256]
    int r = e - 196608;
    int lyr = r >> 16;
    k = (r >> 8) & 255;
    n = r & 255;
    v = W_g[r];
    base = 393216 + (size_t)lyr * 131072;
  }
  size_t pos = base + (size_t)(k >> 5) * 16384 + (size_t)n * 32 + (k & 31);
  short hi = bf16_rne(v);
  short lo = bf16_rne(v - bf16_to_f(hi));
  Wt[pos] = hi;
  Wt[pos + 8192] = lo;
}

// ---------------------------------------------------------------------------
// Split-bf16 MFMA GEMM v2: C[M,256] = A[M,K] @ B[K,256] (fp32 in).
// BM=64, BN=256, BK=32 fp32. 256 threads = 4 waves; wave w owns cols
// [64w,64w+64): 4x4 frags of 16x16x32.
// As double-buffered, ONE barrier per K-step; next A tile prefetched to regs
// during compute; B fragments straight from hi/lo-separated Wt (no B LDS).
// 3 MFMAs per 32k: ah*bh + al*bh + ah*bl (al*bl ~2^-17, dropped).
// EPI==0: fp32 C = relu(A@B + bias[256]);  EPI==1: fp16 C = rowscale[r]*(A@B)
// ---------------------------------------------------------------------------
template <int EPI>
__global__ __launch_bounds__(256) void gemm_mfma(const float* __restrict__ A,
                                                 const short* __restrict__ Wt,
                                                 const float* __restrict__ aux,
                                                 float* __restrict__ C,
                                                 int M, int K) {
  __shared__ short As[2][64][72];   // 64 data shorts ([hi k0..31|lo k0..31]) + 8 pad
  const int t = threadIdx.x;
  const int w = t >> 6, l = t & 63;
  const int g = l >> 4, m16 = l & 15;
  const int row0 = blockIdx.x * 64;
  const int arow = t >> 2, ak = (t & 3) << 3;

  facc4 acc[4][4];
#pragma unroll
  for (int i = 0; i < 4; ++i)
#pragma unroll
    for (int j = 0; j < 4; ++j) acc[i][j] = (facc4)(0.0f);

  const int nsteps = K >> 5;
  const int ga = row0 + arow;
  const bool aval = ga < M;
  const float* aptr = A + (size_t)ga * K + ak;

  float4 f0 = make_float4(0.f, 0.f, 0.f, 0.f), f1 = f0;
  if (aval) {
    f0 = *(const float4*)(aptr);
    f1 = *(const float4*)(aptr + 4);
  }

  int cur = 0;
  for (int s = 0; s < nsteps; ++s) {
    // --- convert tile s (truncation split: hi trunc, lo = trunc(a - hi)) ---
    float av[8] = {f0.x, f0.y, f0.z, f0.w, f1.x, f1.y, f1.z, f1.w};
    bfrag hif, lof;
#pragma unroll
    for (int i = 0; i < 8; ++i) {
      unsigned u = __builtin_bit_cast(unsigned, av[i]);
      hif[i] = (short)(u >> 16);
      float r = av[i] - __builtin_bit_cast(float, u & 0xFFFF0000u);
      lof[i] = (short)(__builtin_bit_cast(unsigned, r) >> 16);
    }
    *(bfrag*)&As[cur][arow][ak] = hif;
    *(bfrag*)&As[cur][arow][32 + ak] = lof;
    // --- prefetch tile s+1 (in flight across the whole compute phase) ---
    if (s + 1 < nsteps && aval) {
      f0 = *(const float4*)(aptr + (size_t)(s + 1) * 32);
      f1 = *(const float4*)(aptr + (size_t)(s + 1) * 32 + 4);
    }
    __syncthreads();
    // --- B fragments straight from global (L2-hot weights) ---
    const short* wb = Wt + ((size_t)s << 14) + (size_t)(w * 64 + m16) * 32 + g * 8;
    bfrag bh[4], bl[4];
#pragma unroll
    for (int nf = 0; nf < 4; ++nf) {
      bh[nf] = *(const bfrag*)(wb + nf * 512);
      bl[nf] = *(const bfrag*)(wb + nf * 512 + 8192);
    }
    // --- A fragments from LDS ---
    bfrag ah[4], al[4];
#pragma unroll
    for (int mf = 0; mf < 4; ++mf) {
      ah[mf] = *(const bfrag*)&As[cur][mf * 16 + m16][g * 8];
      al[mf] = *(const bfrag*)&As[cur][mf * 16 + m16][32 + g * 8];
    }
    // --- 48 MFMAs, same-acc chains spaced 16 apart ---
#pragma unroll
    for (int nf = 0; nf < 4; ++nf)
#pragma unroll
      for (int mf = 0; mf < 4; ++mf)
        acc[mf][nf] = __builtin_amdgcn_mfma_f32_16x16x32_bf16(
            ah[mf], bh[nf], acc[mf][nf], 0, 0, 0);
#pragma unroll
    for (int nf = 0; nf < 4; ++nf)
#pragma unroll
      for (int mf = 0; mf < 4; ++mf)
        acc[mf][nf] = __builtin_amdgcn_mfma_f32_16x16x32_bf16(
            al[mf], bh[nf], acc[mf][nf], 0, 0, 0);
#pragma unroll
    for (int nf = 0; nf < 4; ++nf)
#pragma unroll
      for (int mf = 0; mf < 4; ++mf)
        acc[mf][nf] = __builtin_amdgcn_mfma_f32_16x16x32_bf16(
            ah[mf], bl[nf], acc[mf][nf], 0, 0, 0);
    cur ^= 1;
  }
  // --- epilogue: D layout col=lane&15, row=(lane>>4)*4+reg ---
  const int colbase = w * 64;
  if (EPI == 0) {
#pragma unroll
    for (int nf = 0; nf < 4; ++nf) {
      const float bias = aux[colbase + nf * 16 + m16];
#pragma unroll
      for (int mf = 0; mf < 4; ++mf)
#pragma unroll
        for (int r = 0; r < 4; ++r) {
          int row = row0 + mf * 16 + g * 4 + r;
          if (row < M)
            C[(size_t)row * HIDDEN + colbase + nf * 16 + m16] =
                fmaxf(acc[mf][nf][r] + bias, 0.f);
        }
    }
  } else {
    __half* Ch = (__half*)C;   // fp16 m' for the gather
#pragma unroll
    for (int mf = 0; mf < 4; ++mf)
#pragma unroll
      for (int r = 0; r < 4; ++r) {
        int row = row0 + mf * 16 + g * 4 + r;
        if (row >= M) continue;
        const float sc = aux[row];
#pragma unroll
        for (int nf = 0; nf < 4; ++nf)
          Ch[(size_t)row * HIDDEN + colbase + nf * 16 + m16] =
              __float2half(acc[mf][nf][r] * sc);
      }
  }
}

// ---------------------------------------------------------------------------
// Gather aggregation + bias + BN + ReLU over fp16 m'.
// One wave per node; lane l owns channels 4l..4l+3 (8B = ushort4 per row).
// 8-edge unroll for memory-level parallelism.
// ---------------------------------------------------------------------------
__global__ __launch_bounds__(256) void k_aggregate(
    const unsigned short* __restrict__ mp, const int* __restrict__ row_ptr,
    const int* __restrict__ csr, const float* __restrict__ dinv,
    const float* __restrict__ bg, const float* __restrict__ gamma,
    const float* __restrict__ beta, const float* __restrict__ mean,
    const float* __restrict__ var, float* __restrict__ hout, int N) {
  const int wave = threadIdx.x >> 6, l = threadIdx.x & 63;
  const int v = blockIdx.x * 4 + wave;
  if (v >= N) return;
  const int co = l << 2;  // channel offset of this lane
  ushort4 rs = *(const ushort4*)(mp + (size_t)v * HIDDEN + co);  // self loop
  float4 acc;
  acc.x = h2f(rs.x); acc.y = h2f(rs.y); acc.z = h2f(rs.z); acc.w = h2f(rs.w);
  const int s = row_ptr[v], e = row_ptr[v + 1];
  int i = s;
  for (; i + 8 <= e; i += 8) {
    ushort4 r0 = *(const ushort4*)(mp + (size_t)csr[i + 0] * HIDDEN + co);
    ushort4 r1 = *(const ushort4*)(mp + (size_t)csr[i + 1] * HIDDEN + co);
    ushort4 r2 = *(const ushort4*)(mp + (size_t)csr[i + 2] * HIDDEN + co);
    ushort4 r3 = *(const ushort4*)(mp + (size_t)csr[i + 3] * HIDDEN + co);
    ushort4 r4 = *(const ushort4*)(mp + (size_t)csr[i + 4] * HIDDEN + co);
    ushort4 r5 = *(const ushort4*)(mp + (size_t)csr[i + 5] * HIDDEN + co);
    ushort4 r6 = *(const ushort4*)(mp + (size_t)csr[i + 6] * HIDDEN + co);
    ushort4 r7 = *(const ushort4*)(mp + (size_t)csr[i + 7] * HIDDEN + co);
    acc.x += h2f(r0.x) + h2f(r1.x) + h2f(r2.x) + h2f(r3.x) +
             h2f(r4.x) + h2f(r5.x) + h2f(r6.x) + h2f(r7.x);
    acc.y += h2f(r0.y) + h2f(r1.y) + h2f(r2.y) + h2f(r3.y) +
             h2f(r4.y) + h2f(r5.y) + h2f(r6.y) + h2f(r7.y);
    acc.z += h2f(r0.z) + h2f(r1.z) + h2f(r2.z) + h2f(r3.z) +
             h2f(r4.z) + h2f(r5.z) + h2f(r6.z) + h2f(r7.z);
    acc.w += h2f(r0.w) + h2f(r1.w) + h2f(r2.w) + h2f(r3.w) +
             h2f(r4.w) + h2f(r5.w) + h2f(r6.w) + h2f(r7.w);
  }
  for (; i < e; ++i) {
    ushort4 r0 = *(const ushort4*)(mp + (size_t)csr[i] * HIDDEN + co);
    acc.x += h2f(r0.x);
    acc.y += h2f(r0.y);
    acc.z += h2f(r0.z);
    acc.w += h2f(r0.w);
  }
  const float dv = dinv[v];
  float4 bg4 = *(const float4*)&bg[co];
  float4 g4 = *(const float4*)&gamma[co];
  float4 be4 = *(const float4*)&beta[co];
  float4 mn4 = *(const float4*)&mean[co];
  float4 vr4 = *(const float4*)&var[co];
  float4 o;
  o.x = fmaxf((acc.x * dv + bg4.x - mn4.x) * (g4.x / sqrtf(vr4.x + 1e-5f)) + be4.x, 0.f);
  o.y = fmaxf((acc.y * dv + bg4.y - mn4.y) * (g4.y / sqrtf(vr4.y + 1e-5f)) + be4.y, 0.f);
  o.z = fmaxf((acc.z * dv + bg4.z - mn4.z) * (g4.z / sqrtf(vr4.z + 1e-5f)) + be4.z, 0.f);
  o.w = fmaxf((acc.w * dv + bg4.w - mn4.w) * (g4.w / sqrtf(vr4.w + 1e-5f)) + be4.w, 0.f);
  ((float4*)hout)[(size_t)v * 64 + l] = o;
}

// ---------------------------------------------------------------------------
// Counts via binary search (batch is sorted by construction: jnp.sort)
// ---------------------------------------------------------------------------
__global__ __launch_bounds__(64) void k_count(const int* __restrict__ batch,
                                              float* __restrict__ cnt, int N,
                                              int G) {
  const int g = threadIdx.x;
  if (g >= G) return;
  int lo = 0, hi = N;
  while (lo < hi) {
    int mid = (lo + hi) >> 1;
    if (batch[mid] < g) lo = mid + 1; else hi = mid;
  }
  int lo2 = lo, hi2 = N;
  while (lo2 < hi2) {
    int mid = (lo2 + hi2) >> 1;
    if (batch[mid] < g + 1) lo2 = mid + 1; else hi2 = mid;
  }
  cnt[g] = (float)(lo2 - lo);
}

__global__ __launch_bounds__(256) void k_pool(const float* __restrict__ h,
                                              const int* __restrict__ batch,
                                              float* __restrict__ sums, int N) {
  const int t = threadIdx.x;
  const int start = blockIdx.x * 256;
  if (start >= N) return;
  const int end = min(start + 256, N);
  float acc = 0.f;
  int cur = batch[start];
  for (int n = start; n < end; ++n) {
    int g = batch[n];
    if (g != cur) {
      atomicAdd(&sums[cur * HIDDEN + t], acc);
      acc = 0.f;
      cur = g;
    }
    acc += h[(size_t)n * HIDDEN + t];
  }
  atomicAdd(&sums[cur * HIDDEN + t], acc);
}

// ---------------------------------------------------------------------------
// Head MLP: out = relu(g@W1+b1)@W2+b2, one block per graph
// ---------------------------------------------------------------------------
__global__ __launch_bounds__(128) void k_head(const float* __restrict__ sums,
                                              const float* __restrict__ cnt,
                                              const float* __restrict__ W1,
                                              const float* __restrict__ b1,
                                              const float* __restrict__ W2,
                                              const float* __restrict__ b2,
                                              float* __restrict__ out) {
  __shared__ float gr[256];
  __shared__ float t1[128];
  const int b = blockIdx.x, t = threadIdx.x;
  const float inv = 1.0f / fmaxf(cnt[b], 1.0f);
  gr[t] = sums[b * HIDDEN + t] * inv;
  gr[t + 128] = sums[b * HIDDEN + t + 128] * inv;
  __syncthreads();
  float a = b1[t];
  for (int k = 0; k < 256; ++k) a += gr[k] * W1[k * 128 + t];
  t1[t] = fmaxf(a, 0.f);
  __syncthreads();
  float o = b2[t];
  for (int k = 0; k < 128; ++k) o += t1[k] * W2[k * 128 + t];
  out[b * 128 + t] = o;
}

// ---------------------------------------------------------------------------
extern "C" void kernel_launch(void* const* d_in, const int* in_sizes, int n_in,
                              void* d_out, int out_size, void* d_ws,
                              size_t ws_size, hipStream_t stream) {
  (void)n_in;
  (void)ws_size;
  const float* x = (const float*)d_in[0];
  const int* ei = (const int*)d_in[1];
  const int* batch = (const int*)d_in[2];
  const float* W_in = (const float*)d_in[3];
  const float* b_in = (const float*)d_in[4];
  const float* W_g = (const float*)d_in[5];
  const float* b_g = (const float*)d_in[6];
  const float* bn_gamma = (const float*)d_in[7];
  const float* bn_beta = (const float*)d_in[8];
  const float* bn_mean = (const float*)d_in[9];
  const float* bn_var = (const float*)d_in[10];
  const float* W1 = (const float*)d_in[11];
  const float* b1 = (const float*)d_in[12];
  const float* W2 = (const float*)d_in[13];
  const float* b2 = (const float*)d_in[14];

  const int KIN = 768;
  const int N = in_sizes[0] / KIN;   // 100000
  const int E = in_sizes[1] / 2;     // 1600000
  const int G = out_size / 128;      // 64

  const int* src = ei;
  const int* dst = ei + E;

  char* ws = (char*)d_ws;
  size_t off = 0;
  auto take = [&](size_t bytes) -> void* {
    void* p = ws + off;
    off += (bytes + 255) & ~(size_t)255;
    return p;
  };
  float* h0 = (float*)take((size_t)N * HIDDEN * 4);
  unsigned short* h1 = (unsigned short*)take((size_t)N * HIDDEN * 2);  // fp16 m'
  float* dinv = (float*)take((size_t)N * 4);
  int* deg = (int*)take((size_t)N * 4);
  int* fill = (int*)take((size_t)N * 4);
  int* row_ptr = (int*)take((size_t)(N + 1) * 4);
  int* csr = (int*)take((size_t)E * 4);
  float* sums = (float*)take((size_t)G * HIDDEN * 4);
  float* cnt = (float*)take((size_t)G * 4);
  short* Wt = (short*)take((size_t)(393216 + 3 * 131072) * 2);

  hipMemsetAsync(deg, 0, (size_t)N * 4, stream);
  hipMemsetAsync(fill, 0, (size_t)N * 4, stream);
  hipMemsetAsync(sums, 0, (size_t)G * HIDDEN * 4, stream);

  k_prep_w<<<(196608 + 3 * 65536 + 255) / 256, 256, 0, stream>>>(W_in, W_g, Wt);
  k_hist<<<2048, 256, 0, stream>>>(dst, deg, E);
  k_scan<<<1, 1024, 0, stream>>>(deg, row_ptr, N);
  k_dinv<<<(N + 255) / 256, 256, 0, stream>>>(deg, dinv, N);
  k_fill<<<2048, 256, 0, stream>>>(src, dst, row_ptr, fill, csr, E);

  const int gx = (N + 63) / 64;
  gemm_mfma<0><<<gx, 256, 0, stream>>>(x, Wt, b_in, h0, N, KIN);
  for (int i = 0; i < 3; ++i) {
    gemm_mfma<1><<<gx, 256, 0, stream>>>(h0, Wt + 393216 + (size_t)i * 131072,
                                         dinv, (float*)h1, N, HIDDEN);
    k_aggregate<<<(N + 3) / 4, 256, 0, stream>>>(
        h1, row_ptr, csr, dinv, b_g + i * HIDDEN, bn_gamma + i * HIDDEN,
        bn_beta + i * HIDDEN, bn_mean + i * HIDDEN, bn_var + i * HIDDEN, h0, N);
  }
  k_count<<<1, 64, 0, stream>>>(batch, cnt, N, G);
  k_pool<<<(N + 255) / 256, 256, 0, stream>>>(h0, batch, sums, N);
  k_head<<<G, 128, 0, stream>>>(sums, cnt, W1, b1, W2, b2, (float*)d_out);
}